// Round 20
// baseline (192543.628 us; speedup 1.0000x reference)
//
#include <hip/hip_runtime.h>
#include <stdint.h>

// DSNN bit-exact fp32. Locked-in facts:
//  - Ref is k-ascending single-accumulator fma (absmax 0.0 through R25); any
//    reorder/reprecision flips spikes chaotically. No MFMA (no fp32 MFMA).
//  - R25 (8 waves x 8rows x 4cols, pk_fma dwordx4-W): 30.87 ms = 285 cyc/CU-j.
//    Accounting: VALU 137 (floor ~128) ✓, LDS issue 16xb128x12=192, TCP 128.
//    Gap 285-192 ~ 90 cyc = latency stall: 2 waves/SIMD, 64-cyc pk_fma burst
//    < 120-cyc ds_read + ~200-cyc L2 W latency; occupancy 23.5% (LDS-bound
//    1 block/CU) -> no TLP. VGPR=116: 140 regs headroom.
//  - R26/R27 (this; R26 bench was an infra failure, resubmitted unchanged):
//    manual 1-deep prefetch + unroll 2 (= 2-deep lookahead):
//    issue j+1 spike b128 x2 + W dwordx4 BEFORE PK16(j). +12 VGPR buys
//    ~128 cyc of load->use distance. Same loads, same j-ascending chain ->
//    bit-exact. Model: wall -> ~LDS bound 192-235 -> predict ~23-26 ms.
//    Kill-signal: unchanged ~31 ms => structural plateau.

typedef __attribute__((ext_vector_type(2))) float f32x2;
typedef __attribute__((ext_vector_type(4))) float f32x4;

#define ALPHA 0.9f
#define BETA 0.85f
#define NSTEPS 127
#define WGT 512
#define ROWS 32
#define CPAD 36     // spkbuf col stride (floats): 32 rows + 4 pad
#define HPAD 516    // h0buf row stride (floats)

// Update forms verbatim (bit-exact-verified vs np reference).
#define LIF_L0(M, H, SP) { float _m = BETA * (M) + (H); \
    const bool _b = (_m - 1.0f) > 0.0f; (M) = _b ? 0.0f : _m; \
    (SP) = _b ? 1.0f : 0.0f; }
#define LIF_MID(S, M, A, SP) { (S) = ALPHA * (S) + (A); \
    float _m = BETA * (M) + (S); const bool _b = (_m - 1.0f) > 0.0f; \
    (M) = _b ? 0.0f : _m; (SP) = _b ? 1.0f : 0.0f; }
#define LIF_OUT(S, M, A) { (S) = ALPHA * (S) + (A); (M) = BETA * (M) + (S); }

// Row-pair col-broadcast pk_fma (R14/R25-proven op_sel mapping, absmax 0.0):
// acc[p][c] = f32x2 over rows (2p,2p+1) of col c. src0 = spike row-pair,
// src1 = W col-pair with one col broadcast to both halves:
//   col-lo: op_sel:[0,0,0] op_sel_hi:[1,0,1]
//   col-hi: op_sel:[0,1,0] op_sel_hi:[1,1,1]
// 16 pk_fma: 4 row-pairs x 4 cols (2 W pairs). Each half is an independent
// IEEE f32 fma -> bit-exact chain per (row,col).
#define PK16(Q0, Q1, Q2, Q3, W01, W23) \
    asm("v_pk_fma_f32 %0, %16, %20, %0 op_sel:[0,0,0] op_sel_hi:[1,0,1]\n\t" \
        "v_pk_fma_f32 %1, %16, %20, %1 op_sel:[0,1,0] op_sel_hi:[1,1,1]\n\t" \
        "v_pk_fma_f32 %2, %16, %21, %2 op_sel:[0,0,0] op_sel_hi:[1,0,1]\n\t" \
        "v_pk_fma_f32 %3, %16, %21, %3 op_sel:[0,1,0] op_sel_hi:[1,1,1]\n\t" \
        "v_pk_fma_f32 %4, %17, %20, %4 op_sel:[0,0,0] op_sel_hi:[1,0,1]\n\t" \
        "v_pk_fma_f32 %5, %17, %20, %5 op_sel:[0,1,0] op_sel_hi:[1,1,1]\n\t" \
        "v_pk_fma_f32 %6, %17, %21, %6 op_sel:[0,0,0] op_sel_hi:[1,0,1]\n\t" \
        "v_pk_fma_f32 %7, %17, %21, %7 op_sel:[0,1,0] op_sel_hi:[1,1,1]\n\t" \
        "v_pk_fma_f32 %8, %18, %20, %8 op_sel:[0,0,0] op_sel_hi:[1,0,1]\n\t" \
        "v_pk_fma_f32 %9, %18, %20, %9 op_sel:[0,1,0] op_sel_hi:[1,1,1]\n\t" \
        "v_pk_fma_f32 %10, %18, %21, %10 op_sel:[0,0,0] op_sel_hi:[1,0,1]\n\t" \
        "v_pk_fma_f32 %11, %18, %21, %11 op_sel:[0,1,0] op_sel_hi:[1,1,1]\n\t" \
        "v_pk_fma_f32 %12, %19, %20, %12 op_sel:[0,0,0] op_sel_hi:[1,0,1]\n\t" \
        "v_pk_fma_f32 %13, %19, %20, %13 op_sel:[0,1,0] op_sel_hi:[1,1,1]\n\t" \
        "v_pk_fma_f32 %14, %19, %21, %14 op_sel:[0,0,0] op_sel_hi:[1,0,1]\n\t" \
        "v_pk_fma_f32 %15, %19, %21, %15 op_sel:[0,1,0] op_sel_hi:[1,1,1]" \
        : "+v"(acc[0][0]), "+v"(acc[0][1]), "+v"(acc[0][2]), "+v"(acc[0][3]), \
          "+v"(acc[1][0]), "+v"(acc[1][1]), "+v"(acc[1][2]), "+v"(acc[1][3]), \
          "+v"(acc[2][0]), "+v"(acc[2][1]), "+v"(acc[2][2]), "+v"(acc[2][3]), \
          "+v"(acc[3][0]), "+v"(acc[3][1]), "+v"(acc[3][2]), "+v"(acc[3][3]) \
        : "v"(Q0), "v"(Q1), "v"(Q2), "v"(Q3), "v"(W01), "v"(W23))

__global__ __launch_bounds__(WGT, 2)
void dsnn_kernel(const float* __restrict__ x,
                 const float* __restrict__ W0,
                 const float* __restrict__ W1,
                 const float* __restrict__ W2,
                 float* __restrict__ out)
{
    __shared__ float spkbuf[512 * CPAD];   // 73728 B, [index][row] (x-stage, then spikes)
    __shared__ float h0buf[ROWS * HPAD];   // 66048 B, [row][col]

    const int t  = threadIdx.x;
    const int c4 = (t & 127) * 4;          // cols c4..c4+3
    const int g  = (t >> 7) * 8;           // rows g..g+7 (wave-uniform: 128-thread groups)
    const int r0 = blockIdx.x * ROWS;

    // ---- stage x (pos/neg split) into spkbuf [i][row], i = 0..255 ----
    for (int k = t; k < 256 * ROWS; k += WGT) {
        const int i = k >> 5;
        const int r = k & 31;
        const float v = (i < 128) ? x[(size_t)(r0 + r) * 128 + i]
                                  : -x[(size_t)(r0 + r) * 128 + (i - 128)];
        spkbuf[i * CPAD + r] = fmaxf(v, 0.0f);
    }
    __syncthreads();

    f32x2 acc[4][4];   // [row-pair p][col cc]: rows 2p,2p+1 of col c4+cc

    // acc[p][cc] += buf[j][g+2p+(0,1)] * W[j][c4+cc], j ascending (bit-exact).
    // Software-pipelined: j+1's 2 spike b128 + W dwordx4 issued BEFORE PK16(j).
    auto gemm = [&](const float* Wbase, int K) {
        const float* sb0 = spkbuf + g;
        f32x4 sA = *(const f32x4*)(sb0);
        f32x4 sB = *(const f32x4*)(sb0 + 4);
        f32x4 wv = *(const f32x4*)(Wbase + c4);
        #pragma unroll 2
        for (int j = 0; j < K - 1; ++j) {
            const float* nb = spkbuf + (j + 1) * CPAD + g;
            const f32x4 nA = *(const f32x4*)(nb);
            const f32x4 nB = *(const f32x4*)(nb + 4);
            const f32x4 nw = *(const f32x4*)(Wbase + (size_t)(j + 1) * 512 + c4);
            f32x2 q0 = { sA[0], sA[1] };   // contiguous sub-pairs (no movs)
            f32x2 q1 = { sA[2], sA[3] };
            f32x2 q2 = { sB[0], sB[1] };
            f32x2 q3 = { sB[2], sB[3] };
            f32x2 w01 = { wv[0], wv[1] };
            f32x2 w23 = { wv[2], wv[3] };
            PK16(q0, q1, q2, q3, w01, w23);
            sA = nA; sB = nB; wv = nw;
        }
        {   // epilogue: last j
            f32x2 q0 = { sA[0], sA[1] };
            f32x2 q1 = { sA[2], sA[3] };
            f32x2 q2 = { sB[0], sB[1] };
            f32x2 q3 = { sB[2], sB[3] };
            f32x2 w01 = { wv[0], wv[1] };
            f32x2 w23 = { wv[2], wv[3] };
            PK16(q0, q1, q2, q3, w01, w23);
        }
    };

    // ---- h0 = x @ W0 (time-invariant), park in LDS ----
    #pragma unroll
    for (int p = 0; p < 4; ++p)
        #pragma unroll
        for (int cc = 0; cc < 4; ++cc) acc[p][cc] = (f32x2){0.f, 0.f};
    gemm(W0, 256);
    #pragma unroll
    for (int r = 0; r < 8; ++r) {
        f32x4 hv = { acc[r >> 1][0][r & 1], acc[r >> 1][1][r & 1],
                     acc[r >> 1][2][r & 1], acc[r >> 1][3][r & 1] };
        *(f32x4*)(h0buf + (g + r) * HPAD + c4) = hv;
    }
    __syncthreads();   // all x-reads done before spkbuf is reused for spikes

    // ---- recurrent state in registers: 5 x 8 x 4 = 160 ----
    float m0[8][4], s1[8][4], m1[8][4], s2[8][4], m2[8][4];
    #pragma unroll
    for (int r = 0; r < 8; ++r)
        #pragma unroll
        for (int cc = 0; cc < 4; ++cc) {
            m0[r][cc] = 0.f; s1[r][cc] = 0.f; m1[r][cc] = 0.f;
            s2[r][cc] = 0.f; m2[r][cc] = 0.f;
        }

    for (int step = 0; step < NSTEPS; ++step) {
        // ===== layer 0: m0 = BETA*m0 + h0; spike; reset; spikes -> spkbuf =====
        {
            f32x4 svA[4], svB[4];   // [cc] rows g..g+3 / g+4..g+7
            #pragma unroll
            for (int rr = 0; rr < 4; ++rr) {
                const f32x4 hva = *(const f32x4*)(h0buf + (g + rr) * HPAD + c4);
                const f32x4 hvb = *(const f32x4*)(h0buf + (g + 4 + rr) * HPAD + c4);
                #pragma unroll
                for (int cc = 0; cc < 4; ++cc) {
                    LIF_L0(m0[rr][cc], hva[cc], svA[cc][rr]);
                    LIF_L0(m0[4 + rr][cc], hvb[cc], svB[cc][rr]);
                }
            }
            #pragma unroll
            for (int cc = 0; cc < 4; ++cc) {
                *(f32x4*)(spkbuf + (c4 + cc) * CPAD + g)     = svA[cc];
                *(f32x4*)(spkbuf + (c4 + cc) * CPAD + g + 4) = svB[cc];
            }
        }
        __syncthreads();                       // A: L0 spikes visible

        // ===== layer 1: h1 = spk0 @ W1 =====
        #pragma unroll
        for (int p = 0; p < 4; ++p)
            #pragma unroll
            for (int cc = 0; cc < 4; ++cc) acc[p][cc] = (f32x2){0.f, 0.f};
        gemm(W1, 512);
        __syncthreads();                       // B: all reads of L0 spikes done

        {
            f32x4 svA[4], svB[4];
            #pragma unroll
            for (int rr = 0; rr < 4; ++rr) {
                #pragma unroll
                for (int cc = 0; cc < 4; ++cc) {
                    LIF_MID(s1[rr][cc], m1[rr][cc],
                            acc[rr >> 1][cc][rr & 1], svA[cc][rr]);
                    LIF_MID(s1[4 + rr][cc], m1[4 + rr][cc],
                            acc[(4 + rr) >> 1][cc][rr & 1], svB[cc][rr]);
                }
            }
            #pragma unroll
            for (int cc = 0; cc < 4; ++cc) {
                *(f32x4*)(spkbuf + (c4 + cc) * CPAD + g)     = svA[cc];
                *(f32x4*)(spkbuf + (c4 + cc) * CPAD + g + 4) = svB[cc];
            }
        }
        __syncthreads();                       // C: L1 spikes visible

        // ===== layer 2: h2 = spk1 @ W2; s2,m2 update; no reset =====
        #pragma unroll
        for (int p = 0; p < 4; ++p)
            #pragma unroll
            for (int cc = 0; cc < 4; ++cc) acc[p][cc] = (f32x2){0.f, 0.f};
        gemm(W2, 512);
        #pragma unroll
        for (int r = 0; r < 8; ++r)
            #pragma unroll
            for (int cc = 0; cc < 4; ++cc)
                LIF_OUT(s2[r][cc], m2[r][cc], acc[r >> 1][cc][r & 1]);
        __syncthreads();                       // D: L1-spike reads done before next L0 write
    }

    // ---- write final m2 ----
    #pragma unroll
    for (int r = 0; r < 8; ++r) {
        f32x4 ov = { m2[r][0], m2[r][1], m2[r][2], m2[r][3] };
        *(f32x4*)(out + (size_t)(r0 + g + r) * 512 + c4) = ov;
    }
}

extern "C" void kernel_launch(void* const* d_in, const int* in_sizes, int n_in,
                              void* d_out, int out_size, void* d_ws, size_t ws_size,
                              hipStream_t stream) {
    const float* inputs = (const float*)d_in[0];   // 16384 x 128
    const float* W0     = (const float*)d_in[1];   // 256 x 512
    const float* W1     = (const float*)d_in[2];   // 512 x 512
    const float* W2     = (const float*)d_in[3];   // 512 x 512
    float* out          = (float*)d_out;           // 16384 x 512

    dim3 grid(16384 / ROWS);     // 512 workgroups, 32 rows each
    dim3 block(WGT);             // 8 waves: 4 row-groups x (128 threads x 4 cols)
    dsnn_kernel<<<grid, block, 0, stream>>>(inputs, W0, W1, W2, out);
}

// Round 21
// 30990.234 us; speedup vs baseline: 6.2130x; 6.2130x over previous
//
#include <hip/hip_runtime.h>
#include <stdint.h>

// DSNN bit-exact fp32. Locked-in facts:
//  - Ref is k-ascending single-accumulator fma (absmax 0.0 through R25); any
//    reorder/reprecision flips spikes chaotically. No MFMA (no fp32 MFMA).
//  - R25 (8 waves x 8rows x 4cols, pk_fma dwordx4-W): 30.87 ms = 285 cyc/CU-j.
//    VALU 137 (~floor 128) ✓, LDS issue 16xb128x12=192, TCP 128; gap ~90 cyc
//    = load->use latency at 2 waves/SIMD, 1 block/CU (occupancy 23.5%).
//  - R26 (explicit 1-deep prefetch + unroll 2): CATASTROPHIC 192.5 ms.
//    WRITE_SIZE 32MB->11GB, FETCH 110MB->140GB = SCRATCH SPILLS: rotating
//    pipeline regs live across PK16's 16 "+v" constraints broke the
//    allocator. VALUBusy 7.7%. Lesson: no C-level pipelining around the
//    big asm block (m141/rule-20 analog).
//  - R28 (this): EXACT REVERT to proven R25. Expect 30.8-31.0 ms, VALU 48%,
//    VGPR 116. Remaining gap is structural at this occupancy; next lever
//    (if any): CPAD bank-conflict pad, else plateau.

typedef __attribute__((ext_vector_type(2))) float f32x2;
typedef __attribute__((ext_vector_type(4))) float f32x4;

#define ALPHA 0.9f
#define BETA 0.85f
#define NSTEPS 127
#define WGT 512
#define ROWS 32
#define CPAD 36     // spkbuf col stride (floats): 32 rows + 4 pad
#define HPAD 516    // h0buf row stride (floats)

// Update forms verbatim (bit-exact-verified vs np reference).
#define LIF_L0(M, H, SP) { float _m = BETA * (M) + (H); \
    const bool _b = (_m - 1.0f) > 0.0f; (M) = _b ? 0.0f : _m; \
    (SP) = _b ? 1.0f : 0.0f; }
#define LIF_MID(S, M, A, SP) { (S) = ALPHA * (S) + (A); \
    float _m = BETA * (M) + (S); const bool _b = (_m - 1.0f) > 0.0f; \
    (M) = _b ? 0.0f : _m; (SP) = _b ? 1.0f : 0.0f; }
#define LIF_OUT(S, M, A) { (S) = ALPHA * (S) + (A); (M) = BETA * (M) + (S); }

// Row-pair col-broadcast pk_fma (R14/R25-proven op_sel mapping, absmax 0.0):
// acc[p][c] = f32x2 over rows (2p,2p+1) of col c. src0 = spike row-pair,
// src1 = W col-pair with one col broadcast to both halves:
//   col-lo: op_sel:[0,0,0] op_sel_hi:[1,0,1]
//   col-hi: op_sel:[0,1,0] op_sel_hi:[1,1,1]
// 16 pk_fma: 4 row-pairs x 4 cols (2 W pairs). Each half is an independent
// IEEE f32 fma -> bit-exact chain per (row,col).
#define PK16(Q0, Q1, Q2, Q3, W01, W23) \
    asm("v_pk_fma_f32 %0, %16, %20, %0 op_sel:[0,0,0] op_sel_hi:[1,0,1]\n\t" \
        "v_pk_fma_f32 %1, %16, %20, %1 op_sel:[0,1,0] op_sel_hi:[1,1,1]\n\t" \
        "v_pk_fma_f32 %2, %16, %21, %2 op_sel:[0,0,0] op_sel_hi:[1,0,1]\n\t" \
        "v_pk_fma_f32 %3, %16, %21, %3 op_sel:[0,1,0] op_sel_hi:[1,1,1]\n\t" \
        "v_pk_fma_f32 %4, %17, %20, %4 op_sel:[0,0,0] op_sel_hi:[1,0,1]\n\t" \
        "v_pk_fma_f32 %5, %17, %20, %5 op_sel:[0,1,0] op_sel_hi:[1,1,1]\n\t" \
        "v_pk_fma_f32 %6, %17, %21, %6 op_sel:[0,0,0] op_sel_hi:[1,0,1]\n\t" \
        "v_pk_fma_f32 %7, %17, %21, %7 op_sel:[0,1,0] op_sel_hi:[1,1,1]\n\t" \
        "v_pk_fma_f32 %8, %18, %20, %8 op_sel:[0,0,0] op_sel_hi:[1,0,1]\n\t" \
        "v_pk_fma_f32 %9, %18, %20, %9 op_sel:[0,1,0] op_sel_hi:[1,1,1]\n\t" \
        "v_pk_fma_f32 %10, %18, %21, %10 op_sel:[0,0,0] op_sel_hi:[1,0,1]\n\t" \
        "v_pk_fma_f32 %11, %18, %21, %11 op_sel:[0,1,0] op_sel_hi:[1,1,1]\n\t" \
        "v_pk_fma_f32 %12, %19, %20, %12 op_sel:[0,0,0] op_sel_hi:[1,0,1]\n\t" \
        "v_pk_fma_f32 %13, %19, %20, %13 op_sel:[0,1,0] op_sel_hi:[1,1,1]\n\t" \
        "v_pk_fma_f32 %14, %19, %21, %14 op_sel:[0,0,0] op_sel_hi:[1,0,1]\n\t" \
        "v_pk_fma_f32 %15, %19, %21, %15 op_sel:[0,1,0] op_sel_hi:[1,1,1]" \
        : "+v"(acc[0][0]), "+v"(acc[0][1]), "+v"(acc[0][2]), "+v"(acc[0][3]), \
          "+v"(acc[1][0]), "+v"(acc[1][1]), "+v"(acc[1][2]), "+v"(acc[1][3]), \
          "+v"(acc[2][0]), "+v"(acc[2][1]), "+v"(acc[2][2]), "+v"(acc[2][3]), \
          "+v"(acc[3][0]), "+v"(acc[3][1]), "+v"(acc[3][2]), "+v"(acc[3][3]) \
        : "v"(Q0), "v"(Q1), "v"(Q2), "v"(Q3), "v"(W01), "v"(W23))

__global__ __launch_bounds__(WGT, 2)
void dsnn_kernel(const float* __restrict__ x,
                 const float* __restrict__ W0,
                 const float* __restrict__ W1,
                 const float* __restrict__ W2,
                 float* __restrict__ out)
{
    __shared__ float spkbuf[512 * CPAD];   // 73728 B, [index][row] (x-stage, then spikes)
    __shared__ float h0buf[ROWS * HPAD];   // 66048 B, [row][col]

    const int t  = threadIdx.x;
    const int c4 = (t & 127) * 4;          // cols c4..c4+3
    const int g  = (t >> 7) * 8;           // rows g..g+7 (wave-uniform: 128-thread groups)
    const int r0 = blockIdx.x * ROWS;

    // ---- stage x (pos/neg split) into spkbuf [i][row], i = 0..255 ----
    for (int k = t; k < 256 * ROWS; k += WGT) {
        const int i = k >> 5;
        const int r = k & 31;
        const float v = (i < 128) ? x[(size_t)(r0 + r) * 128 + i]
                                  : -x[(size_t)(r0 + r) * 128 + (i - 128)];
        spkbuf[i * CPAD + r] = fmaxf(v, 0.0f);
    }
    __syncthreads();

    f32x2 acc[4][4];   // [row-pair p][col cc]: rows 2p,2p+1 of col c4+cc

    // acc[p][cc] += buf[j][g+2p+(0,1)] * W[j][c4+cc], j ascending (bit-exact).
    // 2 b128 spike broadcasts + 1 dwordx4 W load + 16 pk_fma per j.
    auto gemm = [&](const float* Wbase, int K) {
        #pragma unroll 2
        for (int j = 0; j < K; ++j) {
            const float* sb = spkbuf + j * CPAD + g;       // wave-uniform -> broadcast
            const f32x4 sA = *(const f32x4*)(sb);          // rows g..g+3
            const f32x4 sB = *(const f32x4*)(sb + 4);      // rows g+4..g+7
            const f32x4 wv = *(const f32x4*)(Wbase + (size_t)j * 512 + c4);
            f32x2 q0 = { sA[0], sA[1] };   // contiguous sub-pairs (no movs)
            f32x2 q1 = { sA[2], sA[3] };
            f32x2 q2 = { sB[0], sB[1] };
            f32x2 q3 = { sB[2], sB[3] };
            f32x2 w01 = { wv[0], wv[1] };
            f32x2 w23 = { wv[2], wv[3] };
            PK16(q0, q1, q2, q3, w01, w23);
        }
    };

    // ---- h0 = x @ W0 (time-invariant), park in LDS ----
    #pragma unroll
    for (int p = 0; p < 4; ++p)
        #pragma unroll
        for (int cc = 0; cc < 4; ++cc) acc[p][cc] = (f32x2){0.f, 0.f};
    gemm(W0, 256);
    #pragma unroll
    for (int r = 0; r < 8; ++r) {
        f32x4 hv = { acc[r >> 1][0][r & 1], acc[r >> 1][1][r & 1],
                     acc[r >> 1][2][r & 1], acc[r >> 1][3][r & 1] };
        *(f32x4*)(h0buf + (g + r) * HPAD + c4) = hv;
    }
    __syncthreads();   // all x-reads done before spkbuf is reused for spikes

    // ---- recurrent state in registers: 5 x 8 x 4 = 160 ----
    float m0[8][4], s1[8][4], m1[8][4], s2[8][4], m2[8][4];
    #pragma unroll
    for (int r = 0; r < 8; ++r)
        #pragma unroll
        for (int cc = 0; cc < 4; ++cc) {
            m0[r][cc] = 0.f; s1[r][cc] = 0.f; m1[r][cc] = 0.f;
            s2[r][cc] = 0.f; m2[r][cc] = 0.f;
        }

    for (int step = 0; step < NSTEPS; ++step) {
        // ===== layer 0: m0 = BETA*m0 + h0; spike; reset; spikes -> spkbuf =====
        {
            f32x4 svA[4], svB[4];   // [cc] rows g..g+3 / g+4..g+7
            #pragma unroll
            for (int rr = 0; rr < 4; ++rr) {
                const f32x4 hva = *(const f32x4*)(h0buf + (g + rr) * HPAD + c4);
                const f32x4 hvb = *(const f32x4*)(h0buf + (g + 4 + rr) * HPAD + c4);
                #pragma unroll
                for (int cc = 0; cc < 4; ++cc) {
                    LIF_L0(m0[rr][cc], hva[cc], svA[cc][rr]);
                    LIF_L0(m0[4 + rr][cc], hvb[cc], svB[cc][rr]);
                }
            }
            #pragma unroll
            for (int cc = 0; cc < 4; ++cc) {
                *(f32x4*)(spkbuf + (c4 + cc) * CPAD + g)     = svA[cc];
                *(f32x4*)(spkbuf + (c4 + cc) * CPAD + g + 4) = svB[cc];
            }
        }
        __syncthreads();                       // A: L0 spikes visible

        // ===== layer 1: h1 = spk0 @ W1 =====
        #pragma unroll
        for (int p = 0; p < 4; ++p)
            #pragma unroll
            for (int cc = 0; cc < 4; ++cc) acc[p][cc] = (f32x2){0.f, 0.f};
        gemm(W1, 512);
        __syncthreads();                       // B: all reads of L0 spikes done

        {
            f32x4 svA[4], svB[4];
            #pragma unroll
            for (int rr = 0; rr < 4; ++rr) {
                #pragma unroll
                for (int cc = 0; cc < 4; ++cc) {
                    LIF_MID(s1[rr][cc], m1[rr][cc],
                            acc[rr >> 1][cc][rr & 1], svA[cc][rr]);
                    LIF_MID(s1[4 + rr][cc], m1[4 + rr][cc],
                            acc[(4 + rr) >> 1][cc][rr & 1], svB[cc][rr]);
                }
            }
            #pragma unroll
            for (int cc = 0; cc < 4; ++cc) {
                *(f32x4*)(spkbuf + (c4 + cc) * CPAD + g)     = svA[cc];
                *(f32x4*)(spkbuf + (c4 + cc) * CPAD + g + 4) = svB[cc];
            }
        }
        __syncthreads();                       // C: L1 spikes visible

        // ===== layer 2: h2 = spk1 @ W2; s2,m2 update; no reset =====
        #pragma unroll
        for (int p = 0; p < 4; ++p)
            #pragma unroll
            for (int cc = 0; cc < 4; ++cc) acc[p][cc] = (f32x2){0.f, 0.f};
        gemm(W2, 512);
        #pragma unroll
        for (int r = 0; r < 8; ++r)
            #pragma unroll
            for (int cc = 0; cc < 4; ++cc)
                LIF_OUT(s2[r][cc], m2[r][cc], acc[r >> 1][cc][r & 1]);
        __syncthreads();                       // D: L1-spike reads done before next L0 write
    }

    // ---- write final m2 ----
    #pragma unroll
    for (int r = 0; r < 8; ++r) {
        f32x4 ov = { m2[r][0], m2[r][1], m2[r][2], m2[r][3] };
        *(f32x4*)(out + (size_t)(r0 + g + r) * 512 + c4) = ov;
    }
}

extern "C" void kernel_launch(void* const* d_in, const int* in_sizes, int n_in,
                              void* d_out, int out_size, void* d_ws, size_t ws_size,
                              hipStream_t stream) {
    const float* inputs = (const float*)d_in[0];   // 16384 x 128
    const float* W0     = (const float*)d_in[1];   // 256 x 512
    const float* W1     = (const float*)d_in[2];   // 512 x 512
    const float* W2     = (const float*)d_in[3];   // 512 x 512
    float* out          = (float*)d_out;           // 16384 x 512

    dim3 grid(16384 / ROWS);     // 512 workgroups, 32 rows each
    dim3 block(WGT);             // 8 waves: 4 row-groups x (128 threads x 4 cols)
    dsnn_kernel<<<grid, block, 0, stream>>>(inputs, W0, W1, W2, out);
}